// Round 6
// baseline (301.690 us; speedup 1.0000x reference)
//
#include <hip/hip_runtime.h>
#include <hip/hip_bf16.h>
#include <math.h>

#define IN_DIM 256
#define HIDDEN 256
#define HEADS 8
#define FPH 32
#define NCLS 40

typedef __attribute__((ext_vector_type(8))) short bf16x8;
typedef __attribute__((ext_vector_type(4))) float f32x4;

__device__ inline unsigned short f2bf(float f) {
    unsigned int u = __float_as_uint(f);
    unsigned int r = (u + 0x7FFF + ((u >> 16) & 1)) >> 16;
    return (unsigned short)r;
}
__device__ inline float bf2f(unsigned short u) {
    return __uint_as_float(((unsigned int)u) << 16);
}

// ---------------- CSR build ----------------
__global__ void hist_kernel(const int* __restrict__ dst, int* __restrict__ deg, int E) {
    int e = blockIdx.x * blockDim.x + threadIdx.x;
    if (e < E) atomicAdd(&deg[dst[e]], 1);
}

__global__ __launch_bounds__(1024) void scan_blocks_kernel(const int* __restrict__ deg,
                                                           int* __restrict__ excl,
                                                           int* __restrict__ bsum, int N) {
    __shared__ int sm[1024];
    int t = threadIdx.x;
    int g = blockIdx.x * 1024 + t;
    int v = (g < N) ? deg[g] : 0;
    sm[t] = v;
    __syncthreads();
    for (int o = 1; o < 1024; o <<= 1) {
        int add = (t >= o) ? sm[t - o] : 0;
        __syncthreads();
        sm[t] += add;
        __syncthreads();
    }
    if (g < N) excl[g] = sm[t] - v;
    if (t == 1023) bsum[blockIdx.x] = sm[1023];
}

__global__ void scan_bsum_kernel(int* __restrict__ bsum, int nb, int* __restrict__ total) {
    if (threadIdx.x == 0 && blockIdx.x == 0) {
        int run = 0;
        for (int i = 0; i < nb; i++) { int v = bsum[i]; bsum[i] = run; run += v; }
        *total = run;
    }
}

__global__ void add_base_kernel(const int* __restrict__ excl, const int* __restrict__ bsum,
                                const int* __restrict__ total, int* __restrict__ offs,
                                int* __restrict__ cursor, int N) {
    int g = blockIdx.x * blockDim.x + threadIdx.x;
    if (g < N) {
        int o = excl[g] + bsum[g >> 10];
        offs[g] = o;
        cursor[g] = o;
    }
    if (g == N) offs[N] = *total;
}

__global__ void fill_kernel(const int* __restrict__ src, const int* __restrict__ dst,
                            int* __restrict__ cursor, int* __restrict__ adjsrc, int E) {
    int e = blockIdx.x * blockDim.x + threadIdx.x;
    if (e < E) {
        int d = dst[e];
        int pos = atomicAdd(&cursor[d], 1);
        adjsrc[pos] = src[e];
    }
}

// ---------------- casts / transposes ----------------
__global__ void cast_x_kernel(const float* __restrict__ x, unsigned short* __restrict__ xb, long n8) {
    long i = (long)blockIdx.x * blockDim.x + threadIdx.x;
    if (i >= n8) return;
    const float4 v0 = *reinterpret_cast<const float4*>(&x[i * 8]);
    const float4 v1 = *reinterpret_cast<const float4*>(&x[i * 8 + 4]);
    ushort4 o0, o1;
    o0.x = f2bf(v0.x); o0.y = f2bf(v0.y); o0.z = f2bf(v0.z); o0.w = f2bf(v0.w);
    o1.x = f2bf(v1.x); o1.y = f2bf(v1.y); o1.z = f2bf(v1.z); o1.w = f2bf(v1.w);
    *reinterpret_cast<ushort4*>(&xb[i * 8]) = o0;
    *reinterpret_cast<ushort4*>(&xb[i * 8 + 4]) = o1;
}

// W1 [256][256] f32 -> W1tb [col][k] bf16
__global__ void transpose_w1_kernel(const float* __restrict__ W, unsigned short* __restrict__ Wt) {
    int t = blockIdx.x * blockDim.x + threadIdx.x;
    if (t >= 256 * 256) return;
    int c = t & 255, k = t >> 8;
    Wt[c * 256 + k] = f2bf(W[k * 256 + c]);
}

// W2 [256][40] f32 -> W2tb [48][256] bf16 (zero pad cols 40..47)
__global__ void transpose_w2_kernel(const float* __restrict__ W, unsigned short* __restrict__ Wt) {
    int t = blockIdx.x * blockDim.x + threadIdx.x;
    if (t >= 48 * 256) return;
    int c = t >> 8, k = t & 255;
    Wt[t] = (c < NCLS) ? f2bf(W[k * NCLS + c]) : (unsigned short)0;
}

// ---------------- GEMM1 MFMA: xb [M,256] x W1tb -> h1b bf16 [M,256] ----------------
__global__ __launch_bounds__(256) void gemm1_mfma(const unsigned short* __restrict__ Ab,
                                                  const unsigned short* __restrict__ Btb,
                                                  unsigned short* __restrict__ Cb, int M) {
    __shared__ unsigned short As[64 * 40];
    __shared__ unsigned short Bs[64 * 40];
    int t = threadIdx.x;
    int wave = t >> 6, lane = t & 63;
    int wr = wave >> 1, wc = wave & 1;
    int rowBase = blockIdx.x * 64;
    int colBase = blockIdx.y * 64;
    int lrow = lane & 15, lk = (lane >> 4) * 8;
    f32x4 acc[2][2] = {};
    int srow = t >> 2, skq = (t & 3) * 8;
    for (int k0 = 0; k0 < 256; k0 += 32) {
        uint4 av = {0, 0, 0, 0};
        int grow = rowBase + srow;
        if (grow < M) av = *reinterpret_cast<const uint4*>(&Ab[(size_t)grow * 256 + k0 + skq]);
        *reinterpret_cast<uint4*>(&As[srow * 40 + skq]) = av;
        uint4 bv = *reinterpret_cast<const uint4*>(&Btb[(size_t)(colBase + srow) * 256 + k0 + skq]);
        *reinterpret_cast<uint4*>(&Bs[srow * 40 + skq]) = bv;
        __syncthreads();
        bf16x8 a0 = *reinterpret_cast<const bf16x8*>(&As[(wr * 32 + lrow) * 40 + lk]);
        bf16x8 a1 = *reinterpret_cast<const bf16x8*>(&As[(wr * 32 + 16 + lrow) * 40 + lk]);
        bf16x8 b0 = *reinterpret_cast<const bf16x8*>(&Bs[(wc * 32 + lrow) * 40 + lk]);
        bf16x8 b1 = *reinterpret_cast<const bf16x8*>(&Bs[(wc * 32 + 16 + lrow) * 40 + lk]);
        acc[0][0] = __builtin_amdgcn_mfma_f32_16x16x32_bf16(a0, b0, acc[0][0], 0, 0, 0);
        acc[0][1] = __builtin_amdgcn_mfma_f32_16x16x32_bf16(a0, b1, acc[0][1], 0, 0, 0);
        acc[1][0] = __builtin_amdgcn_mfma_f32_16x16x32_bf16(a1, b0, acc[1][0], 0, 0, 0);
        acc[1][1] = __builtin_amdgcn_mfma_f32_16x16x32_bf16(a1, b1, acc[1][1], 0, 0, 0);
        __syncthreads();
    }
    int crow0 = rowBase + wr * 32 + (lane >> 4) * 4;
    int ccol0 = colBase + wc * 32 + (lane & 15);
#pragma unroll
    for (int i = 0; i < 2; i++)
#pragma unroll
        for (int j = 0; j < 2; j++)
#pragma unroll
            for (int r = 0; r < 4; r++) {
                int row = crow0 + i * 16 + r;
                if (row < M) Cb[(size_t)row * 256 + ccol0 + j * 16] = f2bf(acc[i][j][r]);
            }
}

// ---------------- GEMM2 MFMA + fused alpha2: out1b [M,256] x W2tb [48,256] -> h2b [M,48], as2/ad2 ----------------
__global__ __launch_bounds__(256) void gemm2_mfma(const unsigned short* __restrict__ Ab,
                                                  const unsigned short* __restrict__ Btb,
                                                  const float* __restrict__ a_src2,
                                                  const float* __restrict__ a_dst2,
                                                  unsigned short* __restrict__ Cb,
                                                  float* __restrict__ as_o,
                                                  float* __restrict__ ad_o, int M) {
    __shared__ unsigned short As[64 * 40];
    __shared__ unsigned short Bs[48 * 40];
    int t = threadIdx.x;
    int wave = t >> 6, lane = t & 63;
    int rowBase = blockIdx.x * 64;
    int lrow = lane & 15, lk = (lane >> 4) * 8;
    f32x4 acc[3] = {};
    int srow = t >> 2, skq = (t & 3) * 8;
    for (int k0 = 0; k0 < 256; k0 += 32) {
        uint4 av = {0, 0, 0, 0};
        int grow = rowBase + srow;
        if (grow < M) av = *reinterpret_cast<const uint4*>(&Ab[(size_t)grow * 256 + k0 + skq]);
        *reinterpret_cast<uint4*>(&As[srow * 40 + skq]) = av;
        if (t < 192) {
            uint4 bv = *reinterpret_cast<const uint4*>(&Btb[(size_t)srow * 256 + k0 + skq]);
            *reinterpret_cast<uint4*>(&Bs[srow * 40 + skq]) = bv;
        }
        __syncthreads();
        bf16x8 a = *reinterpret_cast<const bf16x8*>(&As[(wave * 16 + lrow) * 40 + lk]);
#pragma unroll
        for (int j = 0; j < 3; j++) {
            bf16x8 b = *reinterpret_cast<const bf16x8*>(&Bs[(j * 16 + lrow) * 40 + lk]);
            acc[j] = __builtin_amdgcn_mfma_f32_16x16x32_bf16(a, b, acc[j], 0, 0, 0);
        }
        __syncthreads();
    }
    int ccol = lane & 15;
    int crow0 = rowBase + wave * 16 + (lane >> 4) * 4;
    // per-column alpha weights (cols j*16+ccol; zero for padded cols >= 40)
    float asw[3], adw[3];
#pragma unroll
    for (int j = 0; j < 3; j++) {
        int col = j * 16 + ccol;
        asw[j] = (col < NCLS) ? a_src2[col] : 0.f;
        adw[j] = (col < NCLS) ? a_dst2[col] : 0.f;
    }
#pragma unroll
    for (int r = 0; r < 4; r++) {
        int row = crow0 + r;
        float vs = acc[0][r] * asw[0] + acc[1][r] * asw[1] + acc[2][r] * asw[2];
        float vd = acc[0][r] * adw[0] + acc[1][r] * adw[1] + acc[2][r] * adw[2];
        // reduce across the 16 lanes of this column group
#pragma unroll
        for (int m = 1; m < 16; m <<= 1) {
            vs += __shfl_xor(vs, m, 64);
            vd += __shfl_xor(vd, m, 64);
        }
#pragma unroll
        for (int j = 0; j < 3; j++) {
            if (row < M) Cb[(size_t)row * 48 + j * 16 + ccol] = f2bf(acc[j][r]);
        }
        if (ccol == 0 && row < M) {
            as_o[row] = vs;
            ad_o[row] = vd;
        }
    }
}

// ---------------- alpha layer 1 (bf16 h) ----------------
__global__ void alpha1_kernel(const unsigned short* __restrict__ hb, const float* __restrict__ a_src,
                              const float* __restrict__ a_dst, float* __restrict__ as_o,
                              float* __restrict__ ad_o, int N) {
    int idx = blockIdx.x * blockDim.x + threadIdx.x;
    if (idx >= N * HEADS) return;
    int n = idx >> 3, hd = idx & 7;
    const unsigned short* hp = &hb[(size_t)n * HIDDEN + hd * FPH];
    const float* sp = &a_src[hd * FPH];
    const float* dp = &a_dst[hd * FPH];
    float s = 0.f, d = 0.f;
#pragma unroll
    for (int q = 0; q < 4; q++) {
        uint4 v = *reinterpret_cast<const uint4*>(&hp[q * 8]);
        unsigned int u[4] = {v.x, v.y, v.z, v.w};
#pragma unroll
        for (int e = 0; e < 4; e++) {
            float lo = __uint_as_float(u[e] << 16);
            float hi = __uint_as_float(u[e] & 0xffff0000u);
            int f = q * 8 + e * 2;
            s += lo * sp[f] + hi * sp[f + 1];
            d += lo * dp[f] + hi * dp[f + 1];
        }
    }
    as_o[idx] = s;
    ad_o[idx] = d;
}

// ---------------- aggregation layer 1: one wave per node, 8-deep pipelined gather ----------------
__global__ __launch_bounds__(256) void agg1_kernel(const unsigned short* __restrict__ h1b,
                                                   const float* __restrict__ as,
                                                   const float* __restrict__ ad,
                                                   const int* __restrict__ offs,
                                                   const int* __restrict__ adjsrc,
                                                   const float* __restrict__ b,
                                                   unsigned short* __restrict__ outb, int N) {
    int wid = (blockIdx.x * blockDim.x + threadIdx.x) >> 6;
    int lane = threadIdx.x & 63;
    if (wid >= N) return;
    int n = wid;
    int hd = lane >> 3;
    int beg = offs[n], end = offs[n + 1];
    float adh = ad[n * HEADS + hd];
    float ssum = 0.f;
    float4 acc = {0.f, 0.f, 0.f, 0.f};
    int i = beg;
    for (; i + 8 <= end; i += 8) {
        int sidx[8];
        float av[8];
        ushort4 hv[8];
#pragma unroll
        for (int u = 0; u < 8; u++) sidx[u] = adjsrc[i + u];
#pragma unroll
        for (int u = 0; u < 8; u++) av[u] = as[sidx[u] * HEADS + hd];
#pragma unroll
        for (int u = 0; u < 8; u++)
            hv[u] = *reinterpret_cast<const ushort4*>(&h1b[(size_t)sidx[u] * HIDDEN + lane * 4]);
#pragma unroll
        for (int u = 0; u < 8; u++) {
            float e = av[u] + adh;
            e = e > 0.f ? e : 0.2f * e;
            float ex = __expf(e);
            ssum += ex;
            acc.x += ex * bf2f(hv[u].x);
            acc.y += ex * bf2f(hv[u].y);
            acc.z += ex * bf2f(hv[u].z);
            acc.w += ex * bf2f(hv[u].w);
        }
    }
    for (; i + 4 <= end; i += 4) {
        int sidx[4];
        float av[4];
        ushort4 hv[4];
#pragma unroll
        for (int u = 0; u < 4; u++) sidx[u] = adjsrc[i + u];
#pragma unroll
        for (int u = 0; u < 4; u++) av[u] = as[sidx[u] * HEADS + hd];
#pragma unroll
        for (int u = 0; u < 4; u++)
            hv[u] = *reinterpret_cast<const ushort4*>(&h1b[(size_t)sidx[u] * HIDDEN + lane * 4]);
#pragma unroll
        for (int u = 0; u < 4; u++) {
            float e = av[u] + adh;
            e = e > 0.f ? e : 0.2f * e;
            float ex = __expf(e);
            ssum += ex;
            acc.x += ex * bf2f(hv[u].x);
            acc.y += ex * bf2f(hv[u].y);
            acc.z += ex * bf2f(hv[u].z);
            acc.w += ex * bf2f(hv[u].w);
        }
    }
    for (; i < end; i++) {
        int s = adjsrc[i];
        float e = as[s * HEADS + hd] + adh;
        e = e > 0.f ? e : 0.2f * e;
        float ex = __expf(e);
        ssum += ex;
        ushort4 hv = *reinterpret_cast<const ushort4*>(&h1b[(size_t)s * HIDDEN + lane * 4]);
        acc.x += ex * bf2f(hv.x);
        acc.y += ex * bf2f(hv.y);
        acc.z += ex * bf2f(hv.z);
        acc.w += ex * bf2f(hv.w);
    }
    float inv = 1.f / (ssum + 1e-16f);
    int col = lane * 4;
    float4 o;
    o.x = acc.x * inv + b[col + 0];
    o.y = acc.y * inv + b[col + 1];
    o.z = acc.z * inv + b[col + 2];
    o.w = acc.w * inv + b[col + 3];
    o.x = o.x > 0.f ? o.x : expm1f(o.x);
    o.y = o.y > 0.f ? o.y : expm1f(o.y);
    o.z = o.z > 0.f ? o.z : expm1f(o.z);
    o.w = o.w > 0.f ? o.w : expm1f(o.w);
    ushort4 ob;
    ob.x = f2bf(o.x); ob.y = f2bf(o.y); ob.z = f2bf(o.z); ob.w = f2bf(o.w);
    *reinterpret_cast<ushort4*>(&outb[(size_t)n * HIDDEN + col]) = ob;
}

// ---------------- aggregation layer 2: 8-deep pipelined ----------------
__global__ __launch_bounds__(256) void agg2_kernel(const unsigned short* __restrict__ h2b,
                                                   const float* __restrict__ as,
                                                   const float* __restrict__ ad,
                                                   const int* __restrict__ offs,
                                                   const int* __restrict__ adjsrc,
                                                   const float* __restrict__ b,
                                                   float* __restrict__ out, int N) {
    int wid = (blockIdx.x * blockDim.x + threadIdx.x) >> 6;
    int lane = threadIdx.x & 63;
    if (wid >= N) return;
    int n = wid;
    int beg = offs[n], end = offs[n + 1];
    float adh = ad[n];
    float ssum = 0.f;
    float acc = 0.f;
    bool act = lane < NCLS;
    int i = beg;
    for (; i + 8 <= end; i += 8) {
        int sidx[8];
        float av[8];
        float hv[8];
#pragma unroll
        for (int u = 0; u < 8; u++) sidx[u] = adjsrc[i + u];
#pragma unroll
        for (int u = 0; u < 8; u++) av[u] = as[sidx[u]];
#pragma unroll
        for (int u = 0; u < 8; u++) hv[u] = act ? bf2f(h2b[(size_t)sidx[u] * 48 + lane]) : 0.f;
#pragma unroll
        for (int u = 0; u < 8; u++) {
            float e = av[u] + adh;
            e = e > 0.f ? e : 0.2f * e;
            float ex = __expf(e);
            ssum += ex;
            acc += ex * hv[u];
        }
    }
    for (; i < end; i++) {
        int s = adjsrc[i];
        float e = as[s] + adh;
        e = e > 0.f ? e : 0.2f * e;
        float ex = __expf(e);
        ssum += ex;
        if (act) acc += ex * bf2f(h2b[(size_t)s * 48 + lane]);
    }
    if (act) {
        float inv = 1.f / (ssum + 1e-16f);
        out[(size_t)n * NCLS + lane] = acc * inv + b[lane];
    }
}

extern "C" void kernel_launch(void* const* d_in, const int* in_sizes, int n_in,
                              void* d_out, int out_size, void* d_ws, size_t ws_size,
                              hipStream_t stream) {
    const float* x      = (const float*)d_in[0];
    const int*   ei     = (const int*)d_in[1];
    const float* W1     = (const float*)d_in[2];
    const float* a_src1 = (const float*)d_in[3];
    const float* a_dst1 = (const float*)d_in[4];
    const float* b1     = (const float*)d_in[5];
    const float* W2     = (const float*)d_in[6];
    const float* a_src2 = (const float*)d_in[7];
    const float* a_dst2 = (const float*)d_in[8];
    const float* b2     = (const float*)d_in[9];
    float* out = (float*)d_out;

    const int N = in_sizes[0] / IN_DIM;
    const int E = in_sizes[1] / 2;
    const int* src = ei;
    const int* dst = ei + E;

    char* ws = (char*)d_ws;
    size_t off = 0;
    auto alloc = [&](size_t bytes) {
        void* p = ws + off;
        off = (off + bytes + 255) & ~(size_t)255;
        return p;
    };
    int*   deg    = (int*)alloc((size_t)N * 4);
    int*   excl   = (int*)alloc((size_t)N * 4);
    int*   bsum   = (int*)alloc((size_t)256 * 4);
    int*   total  = (int*)alloc((size_t)4);
    int*   cursor = (int*)alloc((size_t)N * 4);
    int*   offs   = (int*)alloc((size_t)(N + 1) * 4);
    int*   adjsrc = (int*)alloc((size_t)E * 4);
    unsigned short* xb    = (unsigned short*)alloc((size_t)N * IN_DIM * 2);
    unsigned short* W1tb  = (unsigned short*)alloc((size_t)256 * 256 * 2);
    unsigned short* W2tb  = (unsigned short*)alloc((size_t)48 * 256 * 2);
    unsigned short* h1b   = (unsigned short*)alloc((size_t)N * HIDDEN * 2);
    unsigned short* out1b = (unsigned short*)alloc((size_t)N * HIDDEN * 2);
    unsigned short* h2b   = (unsigned short*)alloc((size_t)N * 48 * 2);
    float* as1    = (float*)alloc((size_t)N * HEADS * 4);
    float* ad1    = (float*)alloc((size_t)N * HEADS * 4);
    float* as2    = (float*)alloc((size_t)N * 4);
    float* ad2    = (float*)alloc((size_t)N * 4);

    const int nb = (N + 1023) / 1024;

    hipMemsetAsync(deg, 0, (size_t)N * 4, stream);
    hist_kernel<<<dim3((E + 255) / 256), dim3(256), 0, stream>>>(dst, deg, E);
    scan_blocks_kernel<<<dim3(nb), dim3(1024), 0, stream>>>(deg, excl, bsum, N);
    scan_bsum_kernel<<<dim3(1), dim3(64), 0, stream>>>(bsum, nb, total);
    add_base_kernel<<<dim3((N + 256) / 256), dim3(256), 0, stream>>>(excl, bsum, total, offs, cursor, N);
    fill_kernel<<<dim3((E + 255) / 256), dim3(256), 0, stream>>>(src, dst, cursor, adjsrc, E);

    long n8 = (long)N * IN_DIM / 8;
    cast_x_kernel<<<dim3((n8 + 255) / 256), dim3(256), 0, stream>>>(x, xb, n8);
    transpose_w1_kernel<<<dim3(256), dim3(256), 0, stream>>>(W1, W1tb);
    transpose_w2_kernel<<<dim3(48), dim3(256), 0, stream>>>(W2, W2tb);

    gemm1_mfma<<<dim3((N + 63) / 64, 4), dim3(256), 0, stream>>>(xb, W1tb, h1b, N);
    alpha1_kernel<<<dim3((N * HEADS + 255) / 256), dim3(256), 0, stream>>>(h1b, a_src1, a_dst1, as1, ad1, N);
    agg1_kernel<<<dim3((N + 3) / 4), dim3(256), 0, stream>>>(h1b, as1, ad1, offs, adjsrc, b1, out1b, N);

    gemm2_mfma<<<dim3((N + 63) / 64), dim3(256), 0, stream>>>(out1b, W2tb, a_src2, a_dst2, h2b, as2, ad2, N);
    agg2_kernel<<<dim3((N + 3) / 4), dim3(256), 0, stream>>>(h2b, as2, ad2, offs, adjsrc, b2, out, N);
}

// Round 7
// 298.832 us; speedup vs baseline: 1.0096x; 1.0096x over previous
//
#include <hip/hip_runtime.h>
#include <hip/hip_bf16.h>
#include <math.h>

#define IN_DIM 256
#define HIDDEN 256
#define HEADS 8
#define FPH 32
#define NCLS 40

typedef __attribute__((ext_vector_type(8))) short bf16x8;
typedef __attribute__((ext_vector_type(4))) float f32x4;

__device__ inline unsigned short f2bf(float f) {
    unsigned int u = __float_as_uint(f);
    unsigned int r = (u + 0x7FFF + ((u >> 16) & 1)) >> 16;
    return (unsigned short)r;
}
__device__ inline float bf2f(unsigned short u) {
    return __uint_as_float(((unsigned int)u) << 16);
}

// ---------------- CSR build ----------------
__global__ void hist_kernel(const int* __restrict__ dst, int* __restrict__ deg, int E) {
    int e = blockIdx.x * blockDim.x + threadIdx.x;
    if (e < E) atomicAdd(&deg[dst[e]], 1);
}

__global__ __launch_bounds__(1024) void scan_blocks_kernel(const int* __restrict__ deg,
                                                           int* __restrict__ excl,
                                                           int* __restrict__ bsum, int N) {
    __shared__ int sm[1024];
    int t = threadIdx.x;
    int g = blockIdx.x * 1024 + t;
    int v = (g < N) ? deg[g] : 0;
    sm[t] = v;
    __syncthreads();
    for (int o = 1; o < 1024; o <<= 1) {
        int add = (t >= o) ? sm[t - o] : 0;
        __syncthreads();
        sm[t] += add;
        __syncthreads();
    }
    if (g < N) excl[g] = sm[t] - v;
    if (t == 1023) bsum[blockIdx.x] = sm[1023];
}

__global__ void scan_bsum_kernel(int* __restrict__ bsum, int nb, int* __restrict__ total) {
    if (threadIdx.x == 0 && blockIdx.x == 0) {
        int run = 0;
        for (int i = 0; i < nb; i++) { int v = bsum[i]; bsum[i] = run; run += v; }
        *total = run;
    }
}

__global__ void add_base_kernel(const int* __restrict__ excl, const int* __restrict__ bsum,
                                const int* __restrict__ total, int* __restrict__ offs,
                                int* __restrict__ cursor, int N) {
    int g = blockIdx.x * blockDim.x + threadIdx.x;
    if (g < N) {
        int o = excl[g] + bsum[g >> 10];
        offs[g] = o;
        cursor[g] = o;
    }
    if (g == N) offs[N] = *total;
}

__global__ void fill_kernel(const int* __restrict__ src, const int* __restrict__ dst,
                            int* __restrict__ cursor, int* __restrict__ adjsrc, int E) {
    int e = blockIdx.x * blockDim.x + threadIdx.x;
    if (e < E) {
        int d = dst[e];
        int pos = atomicAdd(&cursor[d], 1);
        adjsrc[pos] = src[e];
    }
}

// ---------------- casts / transposes ----------------
__global__ void cast_x_kernel(const float* __restrict__ x, unsigned short* __restrict__ xb, long n8) {
    long i = (long)blockIdx.x * blockDim.x + threadIdx.x;
    if (i >= n8) return;
    const float4 v0 = *reinterpret_cast<const float4*>(&x[i * 8]);
    const float4 v1 = *reinterpret_cast<const float4*>(&x[i * 8 + 4]);
    ushort4 o0, o1;
    o0.x = f2bf(v0.x); o0.y = f2bf(v0.y); o0.z = f2bf(v0.z); o0.w = f2bf(v0.w);
    o1.x = f2bf(v1.x); o1.y = f2bf(v1.y); o1.z = f2bf(v1.z); o1.w = f2bf(v1.w);
    *reinterpret_cast<ushort4*>(&xb[i * 8]) = o0;
    *reinterpret_cast<ushort4*>(&xb[i * 8 + 4]) = o1;
}

// W1 [256][256] f32 -> W1tb [col][k] bf16
__global__ void transpose_w1_kernel(const float* __restrict__ W, unsigned short* __restrict__ Wt) {
    int t = blockIdx.x * blockDim.x + threadIdx.x;
    if (t >= 256 * 256) return;
    int c = t & 255, k = t >> 8;
    Wt[c * 256 + k] = f2bf(W[k * 256 + c]);
}

// W2 [256][40] f32 -> W2tb [48][256] bf16 (zero pad cols 40..47)
__global__ void transpose_w2_kernel(const float* __restrict__ W, unsigned short* __restrict__ Wt) {
    int t = blockIdx.x * blockDim.x + threadIdx.x;
    if (t >= 48 * 256) return;
    int c = t >> 8, k = t & 255;
    Wt[t] = (c < NCLS) ? f2bf(W[k * NCLS + c]) : (unsigned short)0;
}

// ---------------- GEMM1 MFMA: xb [M,256] x W1tb -> h1b bf16 [M,256] ----------------
__global__ __launch_bounds__(256) void gemm1_mfma(const unsigned short* __restrict__ Ab,
                                                  const unsigned short* __restrict__ Btb,
                                                  unsigned short* __restrict__ Cb, int M) {
    __shared__ unsigned short As[64 * 40];
    __shared__ unsigned short Bs[64 * 40];
    int t = threadIdx.x;
    int wave = t >> 6, lane = t & 63;
    int wr = wave >> 1, wc = wave & 1;
    int rowBase = blockIdx.x * 64;
    int colBase = blockIdx.y * 64;
    int lrow = lane & 15, lk = (lane >> 4) * 8;
    f32x4 acc[2][2] = {};
    int srow = t >> 2, skq = (t & 3) * 8;
    for (int k0 = 0; k0 < 256; k0 += 32) {
        uint4 av = {0, 0, 0, 0};
        int grow = rowBase + srow;
        if (grow < M) av = *reinterpret_cast<const uint4*>(&Ab[(size_t)grow * 256 + k0 + skq]);
        *reinterpret_cast<uint4*>(&As[srow * 40 + skq]) = av;
        uint4 bv = *reinterpret_cast<const uint4*>(&Btb[(size_t)(colBase + srow) * 256 + k0 + skq]);
        *reinterpret_cast<uint4*>(&Bs[srow * 40 + skq]) = bv;
        __syncthreads();
        bf16x8 a0 = *reinterpret_cast<const bf16x8*>(&As[(wr * 32 + lrow) * 40 + lk]);
        bf16x8 a1 = *reinterpret_cast<const bf16x8*>(&As[(wr * 32 + 16 + lrow) * 40 + lk]);
        bf16x8 b0 = *reinterpret_cast<const bf16x8*>(&Bs[(wc * 32 + lrow) * 40 + lk]);
        bf16x8 b1 = *reinterpret_cast<const bf16x8*>(&Bs[(wc * 32 + 16 + lrow) * 40 + lk]);
        acc[0][0] = __builtin_amdgcn_mfma_f32_16x16x32_bf16(a0, b0, acc[0][0], 0, 0, 0);
        acc[0][1] = __builtin_amdgcn_mfma_f32_16x16x32_bf16(a0, b1, acc[0][1], 0, 0, 0);
        acc[1][0] = __builtin_amdgcn_mfma_f32_16x16x32_bf16(a1, b0, acc[1][0], 0, 0, 0);
        acc[1][1] = __builtin_amdgcn_mfma_f32_16x16x32_bf16(a1, b1, acc[1][1], 0, 0, 0);
        __syncthreads();
    }
    int crow0 = rowBase + wr * 32 + (lane >> 4) * 4;
    int ccol0 = colBase + wc * 32 + (lane & 15);
#pragma unroll
    for (int i = 0; i < 2; i++)
#pragma unroll
        for (int j = 0; j < 2; j++)
#pragma unroll
            for (int r = 0; r < 4; r++) {
                int row = crow0 + i * 16 + r;
                if (row < M) Cb[(size_t)row * 256 + ccol0 + j * 16] = f2bf(acc[i][j][r]);
            }
}

// ---------------- GEMM2 MFMA: out1b [M,256] x W2tb [48,256] -> h2b bf16 [M,48] ----------------
__global__ __launch_bounds__(256) void gemm2_mfma(const unsigned short* __restrict__ Ab,
                                                  const unsigned short* __restrict__ Btb,
                                                  unsigned short* __restrict__ Cb, int M) {
    __shared__ unsigned short As[64 * 40];
    __shared__ unsigned short Bs[48 * 40];
    int t = threadIdx.x;
    int wave = t >> 6, lane = t & 63;
    int rowBase = blockIdx.x * 64;
    int lrow = lane & 15, lk = (lane >> 4) * 8;
    f32x4 acc[3] = {};
    int srow = t >> 2, skq = (t & 3) * 8;
    for (int k0 = 0; k0 < 256; k0 += 32) {
        uint4 av = {0, 0, 0, 0};
        int grow = rowBase + srow;
        if (grow < M) av = *reinterpret_cast<const uint4*>(&Ab[(size_t)grow * 256 + k0 + skq]);
        *reinterpret_cast<uint4*>(&As[srow * 40 + skq]) = av;
        if (t < 192) {
            uint4 bv = *reinterpret_cast<const uint4*>(&Btb[(size_t)srow * 256 + k0 + skq]);
            *reinterpret_cast<uint4*>(&Bs[srow * 40 + skq]) = bv;
        }
        __syncthreads();
        bf16x8 a = *reinterpret_cast<const bf16x8*>(&As[(wave * 16 + lrow) * 40 + lk]);
#pragma unroll
        for (int j = 0; j < 3; j++) {
            bf16x8 b = *reinterpret_cast<const bf16x8*>(&Bs[(j * 16 + lrow) * 40 + lk]);
            acc[j] = __builtin_amdgcn_mfma_f32_16x16x32_bf16(a, b, acc[j], 0, 0, 0);
        }
        __syncthreads();
    }
    int crow0 = rowBase + wave * 16 + (lane >> 4) * 4;
    int ccol = lane & 15;
#pragma unroll
    for (int j = 0; j < 3; j++)
#pragma unroll
        for (int r = 0; r < 4; r++) {
            int row = crow0 + r;
            if (row < M) Cb[(size_t)row * 48 + j * 16 + ccol] = f2bf(acc[j][r]);
        }
}

// ---------------- alpha layer 1 (bf16 h) ----------------
__global__ void alpha1_kernel(const unsigned short* __restrict__ hb, const float* __restrict__ a_src,
                              const float* __restrict__ a_dst, float* __restrict__ as_o,
                              float* __restrict__ ad_o, int N) {
    int idx = blockIdx.x * blockDim.x + threadIdx.x;
    if (idx >= N * HEADS) return;
    int n = idx >> 3, hd = idx & 7;
    const unsigned short* hp = &hb[(size_t)n * HIDDEN + hd * FPH];
    const float* sp = &a_src[hd * FPH];
    const float* dp = &a_dst[hd * FPH];
    float s = 0.f, d = 0.f;
#pragma unroll
    for (int q = 0; q < 4; q++) {
        uint4 v = *reinterpret_cast<const uint4*>(&hp[q * 8]);
        unsigned int u[4] = {v.x, v.y, v.z, v.w};
#pragma unroll
        for (int e = 0; e < 4; e++) {
            float lo = __uint_as_float(u[e] << 16);
            float hi = __uint_as_float(u[e] & 0xffff0000u);
            int f = q * 8 + e * 2;
            s += lo * sp[f] + hi * sp[f + 1];
            d += lo * dp[f] + hi * dp[f + 1];
        }
    }
    as_o[idx] = s;
    ad_o[idx] = d;
}

// ---------------- aggregation layer 1: half-wave, 2 edges/iter, 16B gathers ----------------
__global__ __launch_bounds__(256) void agg1_kernel(const unsigned short* __restrict__ h1b,
                                                   const float* __restrict__ as,
                                                   const float* __restrict__ ad,
                                                   const int* __restrict__ offs,
                                                   const int* __restrict__ adjsrc,
                                                   const float* __restrict__ b,
                                                   unsigned short* __restrict__ outb, int N) {
    int wid = (blockIdx.x * blockDim.x + threadIdx.x) >> 6;
    int lane = threadIdx.x & 63;
    if (wid >= N) return;
    int n = wid;
    int l = lane & 31;      // col group: cols l*8 .. l*8+7
    int half = lane >> 5;   // which edge of the pair
    int hd = l >> 2;        // head = (l*8)/32
    int beg = offs[n], end = offs[n + 1];
    float adh = ad[n * HEADS + hd];
    float ssum = 0.f;
    float acc[8] = {};
    int i = beg;
    // main: 8 edges per iteration (4 per half-wave), 4 gathers in flight
    for (; i + 8 <= end; i += 8) {
        int sidx[4];
        float av[4];
        uint4 hv[4];
#pragma unroll
        for (int u = 0; u < 4; u++) sidx[u] = adjsrc[i + 2 * u + half];
#pragma unroll
        for (int u = 0; u < 4; u++) av[u] = as[sidx[u] * HEADS + hd];
#pragma unroll
        for (int u = 0; u < 4; u++)
            hv[u] = *reinterpret_cast<const uint4*>(&h1b[(size_t)sidx[u] * HIDDEN + l * 8]);
#pragma unroll
        for (int u = 0; u < 4; u++) {
            float e = av[u] + adh;
            e = e > 0.f ? e : 0.2f * e;
            float ex = __expf(e);
            ssum += ex;
            unsigned int w0 = hv[u].x, w1 = hv[u].y, w2 = hv[u].z, w3 = hv[u].w;
            acc[0] += ex * __uint_as_float(w0 << 16);
            acc[1] += ex * __uint_as_float(w0 & 0xffff0000u);
            acc[2] += ex * __uint_as_float(w1 << 16);
            acc[3] += ex * __uint_as_float(w1 & 0xffff0000u);
            acc[4] += ex * __uint_as_float(w2 << 16);
            acc[5] += ex * __uint_as_float(w2 & 0xffff0000u);
            acc[6] += ex * __uint_as_float(w3 << 16);
            acc[7] += ex * __uint_as_float(w3 & 0xffff0000u);
        }
    }
    // tail: 2 edges per iteration, predicated
    for (; i < end; i += 2) {
        int idx = i + half;
        if (idx < end) {
            int s = adjsrc[idx];
            float e = as[s * HEADS + hd] + adh;
            e = e > 0.f ? e : 0.2f * e;
            float ex = __expf(e);
            ssum += ex;
            uint4 hv = *reinterpret_cast<const uint4*>(&h1b[(size_t)s * HIDDEN + l * 8]);
            unsigned int w0 = hv.x, w1 = hv.y, w2 = hv.z, w3 = hv.w;
            acc[0] += ex * __uint_as_float(w0 << 16);
            acc[1] += ex * __uint_as_float(w0 & 0xffff0000u);
            acc[2] += ex * __uint_as_float(w1 << 16);
            acc[3] += ex * __uint_as_float(w1 & 0xffff0000u);
            acc[4] += ex * __uint_as_float(w2 << 16);
            acc[5] += ex * __uint_as_float(w2 & 0xffff0000u);
            acc[6] += ex * __uint_as_float(w3 << 16);
            acc[7] += ex * __uint_as_float(w3 & 0xffff0000u);
        }
    }
    // merge the two halves (same node, disjoint edge subsets)
#pragma unroll
    for (int q = 0; q < 8; q++) acc[q] += __shfl_xor(acc[q], 32, 64);
    ssum += __shfl_xor(ssum, 32, 64);
    if (half == 0) {
        float inv = 1.f / (ssum + 1e-16f);
        int col = l * 8;
        unsigned int pk[4];
#pragma unroll
        for (int q = 0; q < 4; q++) {
            float v0 = acc[2 * q] * inv + b[col + 2 * q];
            float v1 = acc[2 * q + 1] * inv + b[col + 2 * q + 1];
            v0 = v0 > 0.f ? v0 : expm1f(v0);
            v1 = v1 > 0.f ? v1 : expm1f(v1);
            pk[q] = (unsigned int)f2bf(v0) | ((unsigned int)f2bf(v1) << 16);
        }
        uint4 o = {pk[0], pk[1], pk[2], pk[3]};
        *reinterpret_cast<uint4*>(&outb[(size_t)n * HIDDEN + col]) = o;
    }
}

// ---------------- alpha layer 2 (bf16 h2 [M,48]) ----------------
__global__ void alpha2_kernel(const unsigned short* __restrict__ hb, const float* __restrict__ a_src,
                              const float* __restrict__ a_dst, float* __restrict__ as_o,
                              float* __restrict__ ad_o, int N) {
    int n = blockIdx.x * blockDim.x + threadIdx.x;
    if (n >= N) return;
    const unsigned short* hp = &hb[(size_t)n * 48];
    float s = 0.f, d = 0.f;
#pragma unroll
    for (int q = 0; q < 5; q++) {
        uint4 v = *reinterpret_cast<const uint4*>(&hp[q * 8]);
        unsigned int u[4] = {v.x, v.y, v.z, v.w};
#pragma unroll
        for (int e = 0; e < 4; e++) {
            float lo = __uint_as_float(u[e] << 16);
            float hi = __uint_as_float(u[e] & 0xffff0000u);
            int f = q * 8 + e * 2;
            s += lo * a_src[f] + hi * a_src[f + 1];
            d += lo * a_dst[f] + hi * a_dst[f + 1];
        }
    }
    as_o[n] = s;
    ad_o[n] = d;
}

// ---------------- aggregation layer 2: 8-deep pipelined ----------------
__global__ __launch_bounds__(256) void agg2_kernel(const unsigned short* __restrict__ h2b,
                                                   const float* __restrict__ as,
                                                   const float* __restrict__ ad,
                                                   const int* __restrict__ offs,
                                                   const int* __restrict__ adjsrc,
                                                   const float* __restrict__ b,
                                                   float* __restrict__ out, int N) {
    int wid = (blockIdx.x * blockDim.x + threadIdx.x) >> 6;
    int lane = threadIdx.x & 63;
    if (wid >= N) return;
    int n = wid;
    int beg = offs[n], end = offs[n + 1];
    float adh = ad[n];
    float ssum = 0.f;
    float acc = 0.f;
    bool act = lane < NCLS;
    int i = beg;
    for (; i + 8 <= end; i += 8) {
        int sidx[8];
        float av[8];
        float hv[8];
#pragma unroll
        for (int u = 0; u < 8; u++) sidx[u] = adjsrc[i + u];
#pragma unroll
        for (int u = 0; u < 8; u++) av[u] = as[sidx[u]];
#pragma unroll
        for (int u = 0; u < 8; u++) hv[u] = act ? bf2f(h2b[(size_t)sidx[u] * 48 + lane]) : 0.f;
#pragma unroll
        for (int u = 0; u < 8; u++) {
            float e = av[u] + adh;
            e = e > 0.f ? e : 0.2f * e;
            float ex = __expf(e);
            ssum += ex;
            acc += ex * hv[u];
        }
    }
    for (; i < end; i++) {
        int s = adjsrc[i];
        float e = as[s] + adh;
        e = e > 0.f ? e : 0.2f * e;
        float ex = __expf(e);
        ssum += ex;
        if (act) acc += ex * bf2f(h2b[(size_t)s * 48 + lane]);
    }
    if (act) {
        float inv = 1.f / (ssum + 1e-16f);
        out[(size_t)n * NCLS + lane] = acc * inv + b[lane];
    }
}

extern "C" void kernel_launch(void* const* d_in, const int* in_sizes, int n_in,
                              void* d_out, int out_size, void* d_ws, size_t ws_size,
                              hipStream_t stream) {
    const float* x      = (const float*)d_in[0];
    const int*   ei     = (const int*)d_in[1];
    const float* W1     = (const float*)d_in[2];
    const float* a_src1 = (const float*)d_in[3];
    const float* a_dst1 = (const float*)d_in[4];
    const float* b1     = (const float*)d_in[5];
    const float* W2     = (const float*)d_in[6];
    const float* a_src2 = (const float*)d_in[7];
    const float* a_dst2 = (const float*)d_in[8];
    const float* b2     = (const float*)d_in[9];
    float* out = (float*)d_out;

    const int N = in_sizes[0] / IN_DIM;
    const int E = in_sizes[1] / 2;
    const int* src = ei;
    const int* dst = ei + E;

    char* ws = (char*)d_ws;
    size_t off = 0;
    auto alloc = [&](size_t bytes) {
        void* p = ws + off;
        off = (off + bytes + 255) & ~(size_t)255;
        return p;
    };
    int*   deg    = (int*)alloc((size_t)N * 4);
    int*   excl   = (int*)alloc((size_t)N * 4);
    int*   bsum   = (int*)alloc((size_t)256 * 4);
    int*   total  = (int*)alloc((size_t)4);
    int*   cursor = (int*)alloc((size_t)N * 4);
    int*   offs   = (int*)alloc((size_t)(N + 1) * 4);
    int*   adjsrc = (int*)alloc((size_t)E * 4);
    unsigned short* xb    = (unsigned short*)alloc((size_t)N * IN_DIM * 2);
    unsigned short* W1tb  = (unsigned short*)alloc((size_t)256 * 256 * 2);
    unsigned short* W2tb  = (unsigned short*)alloc((size_t)48 * 256 * 2);
    unsigned short* h1b   = (unsigned short*)alloc((size_t)N * HIDDEN * 2);
    unsigned short* out1b = (unsigned short*)alloc((size_t)N * HIDDEN * 2);
    unsigned short* h2b   = (unsigned short*)alloc((size_t)N * 48 * 2);
    float* as1    = (float*)alloc((size_t)N * HEADS * 4);
    float* ad1    = (float*)alloc((size_t)N * HEADS * 4);
    float* as2    = (float*)alloc((size_t)N * 4);
    float* ad2    = (float*)alloc((size_t)N * 4);

    const int nb = (N + 1023) / 1024;

    hipMemsetAsync(deg, 0, (size_t)N * 4, stream);
    hist_kernel<<<dim3((E + 255) / 256), dim3(256), 0, stream>>>(dst, deg, E);
    scan_blocks_kernel<<<dim3(nb), dim3(1024), 0, stream>>>(deg, excl, bsum, N);
    scan_bsum_kernel<<<dim3(1), dim3(64), 0, stream>>>(bsum, nb, total);
    add_base_kernel<<<dim3((N + 256) / 256), dim3(256), 0, stream>>>(excl, bsum, total, offs, cursor, N);
    fill_kernel<<<dim3((E + 255) / 256), dim3(256), 0, stream>>>(src, dst, cursor, adjsrc, E);

    long n8 = (long)N * IN_DIM / 8;
    cast_x_kernel<<<dim3((n8 + 255) / 256), dim3(256), 0, stream>>>(x, xb, n8);
    transpose_w1_kernel<<<dim3(256), dim3(256), 0, stream>>>(W1, W1tb);
    transpose_w2_kernel<<<dim3(48), dim3(256), 0, stream>>>(W2, W2tb);

    gemm1_mfma<<<dim3((N + 63) / 64, 4), dim3(256), 0, stream>>>(xb, W1tb, h1b, N);
    alpha1_kernel<<<dim3((N * HEADS + 255) / 256), dim3(256), 0, stream>>>(h1b, a_src1, a_dst1, as1, ad1, N);
    agg1_kernel<<<dim3((N + 3) / 4), dim3(256), 0, stream>>>(h1b, as1, ad1, offs, adjsrc, b1, out1b, N);

    gemm2_mfma<<<dim3((N + 63) / 64), dim3(256), 0, stream>>>(out1b, W2tb, h2b, N);
    alpha2_kernel<<<dim3((N + 255) / 256), dim3(256), 0, stream>>>(h2b, a_src2, a_dst2, as2, ad2, N);
    agg2_kernel<<<dim3((N + 3) / 4), dim3(256), 0, stream>>>(h2b, as2, ad2, offs, adjsrc, b2, out, N);
}

// Round 9
// 271.332 us; speedup vs baseline: 1.1119x; 1.1014x over previous
//
#include <hip/hip_runtime.h>
#include <hip/hip_bf16.h>
#include <math.h>

#define IN_DIM 256
#define HIDDEN 256
#define HEADS 8
#define FPH 32
#define NCLS 40

typedef __attribute__((ext_vector_type(8))) short bf16x8;
typedef __attribute__((ext_vector_type(4))) float f32x4;

__device__ inline unsigned short f2bf(float f) {
    unsigned int u = __float_as_uint(f);
    unsigned int r = (u + 0x7FFF + ((u >> 16) & 1)) >> 16;
    return (unsigned short)r;
}
__device__ inline float bf2f(unsigned short u) {
    return __uint_as_float(((unsigned int)u) << 16);
}

// ---------------- CSR build ----------------
__global__ void hist_kernel(const int* __restrict__ dst, int* __restrict__ deg, int E) {
    int e = blockIdx.x * blockDim.x + threadIdx.x;
    if (e < E) atomicAdd(&deg[dst[e]], 1);
}

__global__ __launch_bounds__(1024) void scan_blocks_kernel(const int* __restrict__ deg,
                                                           int* __restrict__ excl,
                                                           int* __restrict__ bsum, int N) {
    __shared__ int sm[1024];
    int t = threadIdx.x;
    int g = blockIdx.x * 1024 + t;
    int v = (g < N) ? deg[g] : 0;
    sm[t] = v;
    __syncthreads();
    for (int o = 1; o < 1024; o <<= 1) {
        int add = (t >= o) ? sm[t - o] : 0;
        __syncthreads();
        sm[t] += add;
        __syncthreads();
    }
    if (g < N) excl[g] = sm[t] - v;
    if (t == 1023) bsum[blockIdx.x] = sm[1023];
}

__global__ void scan_bsum_kernel(int* __restrict__ bsum, int nb, int* __restrict__ total) {
    if (threadIdx.x == 0 && blockIdx.x == 0) {
        int run = 0;
        for (int i = 0; i < nb; i++) { int v = bsum[i]; bsum[i] = run; run += v; }
        *total = run;
    }
}

__global__ void add_base_kernel(const int* __restrict__ excl, const int* __restrict__ bsum,
                                const int* __restrict__ total, int* __restrict__ offs,
                                int* __restrict__ cursor, int N) {
    int g = blockIdx.x * blockDim.x + threadIdx.x;
    if (g < N) {
        int o = excl[g] + bsum[g >> 10];
        offs[g] = o;
        cursor[g] = o;
    }
    if (g == N) offs[N] = *total;
}

__global__ void fill_kernel(const int* __restrict__ src, const int* __restrict__ dst,
                            int* __restrict__ cursor, int* __restrict__ adjsrc, int E) {
    int e = blockIdx.x * blockDim.x + threadIdx.x;
    if (e < E) {
        int d = dst[e];
        int pos = atomicAdd(&cursor[d], 1);
        adjsrc[pos] = src[e];
    }
}

// ---------------- transposes ----------------
// W1 [256][256] f32 -> W1tb [col][k] bf16
__global__ void transpose_w1_kernel(const float* __restrict__ W, unsigned short* __restrict__ Wt) {
    int t = blockIdx.x * blockDim.x + threadIdx.x;
    if (t >= 256 * 256) return;
    int c = t & 255, k = t >> 8;
    Wt[c * 256 + k] = f2bf(W[k * 256 + c]);
}

// W2 [256][40] f32 -> W2tb [48][256] bf16 (zero pad cols 40..47)
__global__ void transpose_w2_kernel(const float* __restrict__ W, unsigned short* __restrict__ Wt) {
    int t = blockIdx.x * blockDim.x + threadIdx.x;
    if (t >= 48 * 256) return;
    int c = t >> 8, k = t & 255;
    Wt[t] = (c < NCLS) ? f2bf(W[k * NCLS + c]) : (unsigned short)0;
}

// ---------------- GEMM1 MFMA: x f32 [M,256] x W1tb -> h1b bf16 [M,256] ----------------
// One block = 64 rows x ALL 256 cols. 4 waves; wave w owns rows w*16..w*16+15.
// LDS union: K-loop uses [As 64*40 | Bs 256*40] = 12800 ush; epilogue uses Co[64][264] = 16896 ush.
__global__ __launch_bounds__(256) void gemm1_mfma(const float* __restrict__ A,
                                                  const unsigned short* __restrict__ Btb,
                                                  unsigned short* __restrict__ Cb, int M) {
    __shared__ unsigned short smem[64 * 264];  // 16896 >= 64*40 + 256*40
    unsigned short* As = smem;
    unsigned short* Bs = smem + 64 * 40;
    int t = threadIdx.x;
    int wave = t >> 6, lane = t & 63;
    int rowBase = blockIdx.x * 64;
    int lrow = lane & 15, lk = (lane >> 4) * 8;
    f32x4 acc[16] = {};
    int arow = t >> 2, akq = (t & 3) * 8;
    for (int k0 = 0; k0 < 256; k0 += 32) {
        int grow = rowBase + arow;
        float4 a0 = {0.f, 0.f, 0.f, 0.f}, a1 = {0.f, 0.f, 0.f, 0.f};
        if (grow < M) {
            a0 = *reinterpret_cast<const float4*>(&A[(size_t)grow * 256 + k0 + akq]);
            a1 = *reinterpret_cast<const float4*>(&A[(size_t)grow * 256 + k0 + akq + 4]);
        }
        ushort4 p0 = {f2bf(a0.x), f2bf(a0.y), f2bf(a0.z), f2bf(a0.w)};
        ushort4 p1 = {f2bf(a1.x), f2bf(a1.y), f2bf(a1.z), f2bf(a1.w)};
        *reinterpret_cast<ushort4*>(&As[arow * 40 + akq]) = p0;
        *reinterpret_cast<ushort4*>(&As[arow * 40 + akq + 4]) = p1;
#pragma unroll
        for (int q = 0; q < 4; q++) {
            uint4 bv = *reinterpret_cast<const uint4*>(&Btb[(size_t)t * 256 + k0 + q * 8]);
            *reinterpret_cast<uint4*>(&Bs[t * 40 + q * 8]) = bv;
        }
        __syncthreads();
        bf16x8 a = *reinterpret_cast<const bf16x8*>(&As[(wave * 16 + lrow) * 40 + lk]);
#pragma unroll
        for (int j = 0; j < 16; j++) {
            bf16x8 b = *reinterpret_cast<const bf16x8*>(&Bs[(j * 16 + lrow) * 40 + lk]);
            acc[j] = __builtin_amdgcn_mfma_f32_16x16x32_bf16(a, b, acc[j], 0, 0, 0);
        }
        __syncthreads();
    }
    // epilogue: acc -> LDS (bf16) -> coalesced global write
    unsigned short* Co = smem;  // [64][264]
    int r0 = (lane >> 4) * 4;
#pragma unroll
    for (int j = 0; j < 16; j++)
#pragma unroll
        for (int r = 0; r < 4; r++)
            Co[(wave * 16 + r0 + r) * 264 + j * 16 + lrow] = f2bf(acc[j][r]);
    __syncthreads();
    int wrow = t >> 2, wchunk = (t & 3) * 64;
    int growW = rowBase + wrow;
    if (growW < M) {
#pragma unroll
        for (int q = 0; q < 8; q++) {
            uint4 v = *reinterpret_cast<const uint4*>(&Co[wrow * 264 + wchunk + q * 8]);
            *reinterpret_cast<uint4*>(&Cb[(size_t)growW * 256 + wchunk + q * 8]) = v;
        }
    }
}

// ---------------- GEMM2 MFMA: out1b [M,256] x W2tb [48,256] -> h2b bf16 [M,48] ----------------
__global__ __launch_bounds__(256) void gemm2_mfma(const unsigned short* __restrict__ Ab,
                                                  const unsigned short* __restrict__ Btb,
                                                  unsigned short* __restrict__ Cb, int M) {
    __shared__ unsigned short As[64 * 40];
    __shared__ unsigned short Bs[48 * 40];
    int t = threadIdx.x;
    int wave = t >> 6, lane = t & 63;
    int rowBase = blockIdx.x * 64;
    int lrow = lane & 15, lk = (lane >> 4) * 8;
    f32x4 acc[3] = {};
    int srow = t >> 2, skq = (t & 3) * 8;
    for (int k0 = 0; k0 < 256; k0 += 32) {
        uint4 av = {0, 0, 0, 0};
        int grow = rowBase + srow;
        if (grow < M) av = *reinterpret_cast<const uint4*>(&Ab[(size_t)grow * 256 + k0 + skq]);
        *reinterpret_cast<uint4*>(&As[srow * 40 + skq]) = av;
        if (t < 192) {
            uint4 bv = *reinterpret_cast<const uint4*>(&Btb[(size_t)srow * 256 + k0 + skq]);
            *reinterpret_cast<uint4*>(&Bs[srow * 40 + skq]) = bv;
        }
        __syncthreads();
        bf16x8 a = *reinterpret_cast<const bf16x8*>(&As[(wave * 16 + lrow) * 40 + lk]);
#pragma unroll
        for (int j = 0; j < 3; j++) {
            bf16x8 b = *reinterpret_cast<const bf16x8*>(&Bs[(j * 16 + lrow) * 40 + lk]);
            acc[j] = __builtin_amdgcn_mfma_f32_16x16x32_bf16(a, b, acc[j], 0, 0, 0);
        }
        __syncthreads();
    }
    int crow0 = rowBase + wave * 16 + (lane >> 4) * 4;
    int ccol = lane & 15;
#pragma unroll
    for (int j = 0; j < 3; j++)
#pragma unroll
        for (int r = 0; r < 4; r++) {
            int row = crow0 + r;
            if (row < M) Cb[(size_t)row * 48 + j * 16 + ccol] = f2bf(acc[j][r]);
        }
}

// ---------------- alpha layer 1 (bf16 h) ----------------
__global__ void alpha1_kernel(const unsigned short* __restrict__ hb, const float* __restrict__ a_src,
                              const float* __restrict__ a_dst, float* __restrict__ as_o,
                              float* __restrict__ ad_o, int N) {
    int idx = blockIdx.x * blockDim.x + threadIdx.x;
    if (idx >= N * HEADS) return;
    int n = idx >> 3, hd = idx & 7;
    const unsigned short* hp = &hb[(size_t)n * HIDDEN + hd * FPH];
    const float* sp = &a_src[hd * FPH];
    const float* dp = &a_dst[hd * FPH];
    float s = 0.f, d = 0.f;
#pragma unroll
    for (int q = 0; q < 4; q++) {
        uint4 v = *reinterpret_cast<const uint4*>(&hp[q * 8]);
        unsigned int u[4] = {v.x, v.y, v.z, v.w};
#pragma unroll
        for (int e = 0; e < 4; e++) {
            float lo = __uint_as_float(u[e] << 16);
            float hi = __uint_as_float(u[e] & 0xffff0000u);
            int f = q * 8 + e * 2;
            s += lo * sp[f] + hi * sp[f + 1];
            d += lo * dp[f] + hi * dp[f + 1];
        }
    }
    as_o[idx] = s;
    ad_o[idx] = d;
}

// ---------------- aggregation layer 1: one wave per node, 8-deep pipelined gather ----------------
__global__ __launch_bounds__(256) void agg1_kernel(const unsigned short* __restrict__ h1b,
                                                   const float* __restrict__ as,
                                                   const float* __restrict__ ad,
                                                   const int* __restrict__ offs,
                                                   const int* __restrict__ adjsrc,
                                                   const float* __restrict__ b,
                                                   unsigned short* __restrict__ outb, int N) {
    int wid = (blockIdx.x * blockDim.x + threadIdx.x) >> 6;
    int lane = threadIdx.x & 63;
    if (wid >= N) return;
    int n = wid;
    int hd = lane >> 3;
    int beg = offs[n], end = offs[n + 1];
    float adh = ad[n * HEADS + hd];
    float ssum = 0.f;
    float4 acc = {0.f, 0.f, 0.f, 0.f};
    int i = beg;
    for (; i + 8 <= end; i += 8) {
        int sidx[8];
        float av[8];
        ushort4 hv[8];
#pragma unroll
        for (int u = 0; u < 8; u++) sidx[u] = adjsrc[i + u];
#pragma unroll
        for (int u = 0; u < 8; u++) av[u] = as[sidx[u] * HEADS + hd];
#pragma unroll
        for (int u = 0; u < 8; u++)
            hv[u] = *reinterpret_cast<const ushort4*>(&h1b[(size_t)sidx[u] * HIDDEN + lane * 4]);
#pragma unroll
        for (int u = 0; u < 8; u++) {
            float e = av[u] + adh;
            e = e > 0.f ? e : 0.2f * e;
            float ex = __expf(e);
            ssum += ex;
            acc.x += ex * bf2f(hv[u].x);
            acc.y += ex * bf2f(hv[u].y);
            acc.z += ex * bf2f(hv[u].z);
            acc.w += ex * bf2f(hv[u].w);
        }
    }
    for (; i + 4 <= end; i += 4) {
        int sidx[4];
        float av[4];
        ushort4 hv[4];
#pragma unroll
        for (int u = 0; u < 4; u++) sidx[u] = adjsrc[i + u];
#pragma unroll
        for (int u = 0; u < 4; u++) av[u] = as[sidx[u] * HEADS + hd];
#pragma unroll
        for (int u = 0; u < 4; u++)
            hv[u] = *reinterpret_cast<const ushort4*>(&h1b[(size_t)sidx[u] * HIDDEN + lane * 4]);
#pragma unroll
        for (int u = 0; u < 4; u++) {
            float e = av[u] + adh;
            e = e > 0.f ? e : 0.2f * e;
            float ex = __expf(e);
            ssum += ex;
            acc.x += ex * bf2f(hv[u].x);
            acc.y += ex * bf2f(hv[u].y);
            acc.z += ex * bf2f(hv[u].z);
            acc.w += ex * bf2f(hv[u].w);
        }
    }
    for (; i < end; i++) {
        int s = adjsrc[i];
        float e = as[s * HEADS + hd] + adh;
        e = e > 0.f ? e : 0.2f * e;
        float ex = __expf(e);
        ssum += ex;
        ushort4 hv = *reinterpret_cast<const ushort4*>(&h1b[(size_t)s * HIDDEN + lane * 4]);
        acc.x += ex * bf2f(hv.x);
        acc.y += ex * bf2f(hv.y);
        acc.z += ex * bf2f(hv.z);
        acc.w += ex * bf2f(hv.w);
    }
    float inv = 1.f / (ssum + 1e-16f);
    int col = lane * 4;
    float4 o;
    o.x = acc.x * inv + b[col + 0];
    o.y = acc.y * inv + b[col + 1];
    o.z = acc.z * inv + b[col + 2];
    o.w = acc.w * inv + b[col + 3];
    o.x = o.x > 0.f ? o.x : expm1f(o.x);
    o.y = o.y > 0.f ? o.y : expm1f(o.y);
    o.z = o.z > 0.f ? o.z : expm1f(o.z);
    o.w = o.w > 0.f ? o.w : expm1f(o.w);
    ushort4 ob;
    ob.x = f2bf(o.x); ob.y = f2bf(o.y); ob.z = f2bf(o.z); ob.w = f2bf(o.w);
    *reinterpret_cast<ushort4*>(&outb[(size_t)n * HIDDEN + col]) = ob;
}

// ---------------- alpha layer 2 (bf16 h2 [M,48]) ----------------
__global__ void alpha2_kernel(const unsigned short* __restrict__ hb, const float* __restrict__ a_src,
                              const float* __restrict__ a_dst, float* __restrict__ as_o,
                              float* __restrict__ ad_o, int N) {
    int n = blockIdx.x * blockDim.x + threadIdx.x;
    if (n >= N) return;
    const unsigned short* hp = &hb[(size_t)n * 48];
    float s = 0.f, d = 0.f;
#pragma unroll
    for (int q = 0; q < 5; q++) {
        uint4 v = *reinterpret_cast<const uint4*>(&hp[q * 8]);
        unsigned int u[4] = {v.x, v.y, v.z, v.w};
#pragma unroll
        for (int e = 0; e < 4; e++) {
            float lo = __uint_as_float(u[e] << 16);
            float hi = __uint_as_float(u[e] & 0xffff0000u);
            int f = q * 8 + e * 2;
            s += lo * a_src[f] + hi * a_src[f + 1];
            d += lo * a_dst[f] + hi * a_dst[f + 1];
        }
    }
    as_o[n] = s;
    ad_o[n] = d;
}

// ---------------- aggregation layer 2: 4-deep pipelined (R4-proven form) ----------------
__global__ __launch_bounds__(256) void agg2_kernel(const unsigned short* __restrict__ h2b,
                                                   const float* __restrict__ as,
                                                   const float* __restrict__ ad,
                                                   const int* __restrict__ offs,
                                                   const int* __restrict__ adjsrc,
                                                   const float* __restrict__ b,
                                                   float* __restrict__ out, int N) {
    int wid = (blockIdx.x * blockDim.x + threadIdx.x) >> 6;
    int lane = threadIdx.x & 63;
    if (wid >= N) return;
    int n = wid;
    int beg = offs[n], end = offs[n + 1];
    float adh = ad[n];
    float ssum = 0.f;
    float acc = 0.f;
    bool act = lane < NCLS;
    int i = beg;
    for (; i + 4 <= end; i += 4) {
        int s0 = adjsrc[i + 0];
        int s1 = adjsrc[i + 1];
        int s2 = adjsrc[i + 2];
        int s3 = adjsrc[i + 3];
        float a0 = as[s0];
        float a1 = as[s1];
        float a2 = as[s2];
        float a3 = as[s3];
        float h0 = 0.f, h1 = 0.f, h2 = 0.f, h3 = 0.f;
        if (act) {
            h0 = bf2f(h2b[(size_t)s0 * 48 + lane]);
            h1 = bf2f(h2b[(size_t)s1 * 48 + lane]);
            h2 = bf2f(h2b[(size_t)s2 * 48 + lane]);
            h3 = bf2f(h2b[(size_t)s3 * 48 + lane]);
        }
        float e0 = a0 + adh; e0 = e0 > 0.f ? e0 : 0.2f * e0; float x0 = __expf(e0);
        float e1 = a1 + adh; e1 = e1 > 0.f ? e1 : 0.2f * e1; float x1 = __expf(e1);
        float e2 = a2 + adh; e2 = e2 > 0.f ? e2 : 0.2f * e2; float x2 = __expf(e2);
        float e3 = a3 + adh; e3 = e3 > 0.f ? e3 : 0.2f * e3; float x3 = __expf(e3);
        ssum += (x0 + x1) + (x2 + x3);
        acc += x0 * h0 + x1 * h1 + x2 * h2 + x3 * h3;
    }
    for (; i < end; i++) {
        int s = adjsrc[i];
        float e = as[s] + adh;
        e = e > 0.f ? e : 0.2f * e;
        float ex = __expf(e);
        ssum += ex;
        if (act) acc += ex * bf2f(h2b[(size_t)s * 48 + lane]);
    }
    if (act) {
        float inv = 1.f / (ssum + 1e-16f);
        out[(size_t)n * NCLS + lane] = acc * inv + b[lane];
    }
}

extern "C" void kernel_launch(void* const* d_in, const int* in_sizes, int n_in,
                              void* d_out, int out_size, void* d_ws, size_t ws_size,
                              hipStream_t stream) {
    const float* x      = (const float*)d_in[0];
    const int*   ei     = (const int*)d_in[1];
    const float* W1     = (const float*)d_in[2];
    const float* a_src1 = (const float*)d_in[3];
    const float* a_dst1 = (const float*)d_in[4];
    const float* b1     = (const float*)d_in[5];
    const float* W2     = (const float*)d_in[6];
    const float* a_src2 = (const float*)d_in[7];
    const float* a_dst2 = (const float*)d_in[8];
    const float* b2     = (const float*)d_in[9];
    float* out = (float*)d_out;

    const int N = in_sizes[0] / IN_DIM;
    const int E = in_sizes[1] / 2;
    const int* src = ei;
    const int* dst = ei + E;

    char* ws = (char*)d_ws;
    size_t off = 0;
    auto alloc = [&](size_t bytes) {
        void* p = ws + off;
        off = (off + bytes + 255) & ~(size_t)255;
        return p;
    };
    int*   deg    = (int*)alloc((size_t)N * 4);
    int*   excl   = (int*)alloc((size_t)N * 4);
    int*   bsum   = (int*)alloc((size_t)256 * 4);
    int*   total  = (int*)alloc((size_t)4);
    int*   cursor = (int*)alloc((size_t)N * 4);
    int*   offs   = (int*)alloc((size_t)(N + 1) * 4);
    int*   adjsrc = (int*)alloc((size_t)E * 4);
    unsigned short* W1tb  = (unsigned short*)alloc((size_t)256 * 256 * 2);
    unsigned short* W2tb  = (unsigned short*)alloc((size_t)48 * 256 * 2);
    unsigned short* h1b   = (unsigned short*)alloc((size_t)N * HIDDEN * 2);
    unsigned short* out1b = (unsigned short*)alloc((size_t)N * HIDDEN * 2);
    unsigned short* h2b   = (unsigned short*)alloc((size_t)N * 48 * 2);
    float* as1    = (float*)alloc((size_t)N * HEADS * 4);
    float* ad1    = (float*)alloc((size_t)N * HEADS * 4);
    float* as2    = (float*)alloc((size_t)N * 4);
    float* ad2    = (float*)alloc((size_t)N * 4);

    const int nb = (N + 1023) / 1024;

    hipMemsetAsync(deg, 0, (size_t)N * 4, stream);
    hist_kernel<<<dim3((E + 255) / 256), dim3(256), 0, stream>>>(dst, deg, E);
    scan_blocks_kernel<<<dim3(nb), dim3(1024), 0, stream>>>(deg, excl, bsum, N);
    scan_bsum_kernel<<<dim3(1), dim3(64), 0, stream>>>(bsum, nb, total);
    add_base_kernel<<<dim3((N + 256) / 256), dim3(256), 0, stream>>>(excl, bsum, total, offs, cursor, N);
    fill_kernel<<<dim3((E + 255) / 256), dim3(256), 0, stream>>>(src, dst, cursor, adjsrc, E);

    transpose_w1_kernel<<<dim3(256), dim3(256), 0, stream>>>(W1, W1tb);
    transpose_w2_kernel<<<dim3(48), dim3(256), 0, stream>>>(W2, W2tb);

    gemm1_mfma<<<dim3((N + 63) / 64), dim3(256), 0, stream>>>(x, W1tb, h1b, N);
    alpha1_kernel<<<dim3((N * HEADS + 255) / 256), dim3(256), 0, stream>>>(h1b, a_src1, a_dst1, as1, ad1, N);
    agg1_kernel<<<dim3((N + 3) / 4), dim3(256), 0, stream>>>(h1b, as1, ad1, offs, adjsrc, b1, out1b, N);

    gemm2_mfma<<<dim3((N + 63) / 64), dim3(256), 0, stream>>>(out1b, W2tb, h2b, N);
    alpha2_kernel<<<dim3((N + 255) / 256), dim3(256), 0, stream>>>(h2b, a_src2, a_dst2, as2, ad2, N);
    agg2_kernel<<<dim3((N + 3) / 4), dim3(256), 0, stream>>>(h2b, as2, ad2, offs, adjsrc, b2, out, N);
}